// Round 1
// baseline (103.717 us; speedup 1.0000x reference)
//
#include <hip/hip_runtime.h>
#include <hip/hip_bf16.h>
#include <math.h>

// Problem constants (from reference setup_inputs):
// B=4, Q=100, T=20, H=W=128 (HW=16384), C=80
#define B_ 4
#define Q_ 100
#define T_ 20
#define C_ 80
#define HW_ 16384

__device__ __forceinline__ float wave_reduce_sum(float v) {
    // 64-lane wave
    v += __shfl_down(v, 32);
    v += __shfl_down(v, 16);
    v += __shfl_down(v, 8);
    v += __shfl_down(v, 4);
    v += __shfl_down(v, 2);
    v += __shfl_down(v, 1);
    return v;
}

// Kernel 1: per-(b,t) sum of target masks -> tsum[b*T+t]
__global__ __launch_bounds__(256) void tgt_sum_kernel(const float* __restrict__ tgt,
                                                      float* __restrict__ tsum) {
    const int bt = blockIdx.x;             // 0..B*T-1
    const float4* p = (const float4*)(tgt + (size_t)bt * HW_);
    const int N4 = HW_ / 4;                // 4096
    float s = 0.f;
    for (int i = threadIdx.x; i < N4; i += blockDim.x) {
        float4 v = p[i];
        s += v.x + v.y + v.z + v.w;
    }
    s = wave_reduce_sum(s);
    __shared__ float red[4];
    const int lane = threadIdx.x & 63;
    const int wave = threadIdx.x >> 6;
    if (lane == 0) red[wave] = s;
    __syncthreads();
    if (threadIdx.x == 0) {
        tsum[bt] = red[0] + red[1] + red[2] + red[3];
    }
}

// Kernel 2: one block per (b,q). Computes all T costs.
__global__ __launch_bounds__(256) void cost_kernel(const float* __restrict__ probs,
                                                   const float* __restrict__ outm,
                                                   const float* __restrict__ tgtm,
                                                   const int*   __restrict__ labels,
                                                   const float* __restrict__ tsum,
                                                   float* __restrict__ out) {
    const int bq = blockIdx.x;         // 0..B*Q-1
    const int b = bq / Q_;
    const int q = bq % Q_;

    const float4* o4 = (const float4*)(outm + ((size_t)b * Q_ + q) * HW_);
    const float4* g4 = (const float4*)(tgtm + (size_t)b * T_ * HW_);
    const int N4 = HW_ / 4;            // 4096

    float accL[T_];
    float accI[T_];
#pragma unroll
    for (int t = 0; t < T_; ++t) { accL[t] = 0.f; accI[t] = 0.f; }
    float osum = 0.f;

    for (int i = threadIdx.x; i < N4; i += 256) {
        float4 o = o4[i];
        osum += (o.x + o.y) + (o.z + o.w);
#pragma unroll
        for (int t = 0; t < T_; ++t) {
            float4 g = g4[t * N4 + i];
            accL[t] += (fabsf(o.x - g.x) + fabsf(o.y - g.y)) +
                       (fabsf(o.z - g.z) + fabsf(o.w - g.w));
            accI[t] = fmaf(o.x, g.x, accI[t]);
            accI[t] = fmaf(o.y, g.y, accI[t]);
            accI[t] = fmaf(o.z, g.z, accI[t]);
            accI[t] = fmaf(o.w, g.w, accI[t]);
        }
    }

    // Block reduction: 4 waves -> LDS -> final 41 sums
    const int lane = threadIdx.x & 63;
    const int wave = threadIdx.x >> 6;
    __shared__ float red[4][2 * T_ + 1];
#pragma unroll
    for (int t = 0; t < T_; ++t) {
        float vL = wave_reduce_sum(accL[t]);
        float vI = wave_reduce_sum(accI[t]);
        if (lane == 0) { red[wave][t] = vL; red[wave][T_ + t] = vI; }
    }
    {
        float vo = wave_reduce_sum(osum);
        if (lane == 0) red[wave][2 * T_] = vo;
    }

    // Softmax logits staging
    __shared__ float s_logit[C_];
    if (threadIdx.x < C_) {
        s_logit[threadIdx.x] = probs[((size_t)b * Q_ + q) * C_ + threadIdx.x];
    }
    __syncthreads();

    __shared__ float fin[2 * T_ + 1];
    if (threadIdx.x < 2 * T_ + 1) {
        fin[threadIdx.x] = red[0][threadIdx.x] + red[1][threadIdx.x] +
                           red[2][threadIdx.x] + red[3][threadIdx.x];
    }
    __syncthreads();

    if (threadIdx.x < T_) {
        const int t = threadIdx.x;
        // softmax over 80 logits (redundant across 20 lanes; trivial cost)
        float m = -INFINITY;
#pragma unroll
        for (int c = 0; c < C_; ++c) m = fmaxf(m, s_logit[c]);
        float s = 0.f;
#pragma unroll
        for (int c = 0; c < C_; ++c) s += __expf(s_logit[c] - m);
        const int lab = labels[b * T_ + t];
        const float p = __expf(s_logit[lab] - m) / s;
        const float cost_class = -p;

        const float L = fin[t];
        const float I = fin[T_ + t];
        const float os = fin[2 * T_];
        const float denom = os + tsum[b * T_ + t];
        const float cost_dice = 1.f - (2.f * I + 1.f) / (denom + 1.f);

        out[((size_t)b * Q_ + q) * T_ + t] = L + cost_class + cost_dice;
    }
}

extern "C" void kernel_launch(void* const* d_in, const int* in_sizes, int n_in,
                              void* d_out, int out_size, void* d_ws, size_t ws_size,
                              hipStream_t stream) {
    const float* out_probs    = (const float*)d_in[0]; // [B,Q,C]
    const float* out_masks    = (const float*)d_in[1]; // [B,Q,H,W]
    const float* target_masks = (const float*)d_in[2]; // [B,T,H,W]
    const int*   target_labels= (const int*)d_in[3];   // [B,T]
    float* out = (float*)d_out;                        // [B,Q,T]
    float* tsum = (float*)d_ws;                        // B*T floats

    tgt_sum_kernel<<<B_ * T_, 256, 0, stream>>>(target_masks, tsum);
    cost_kernel<<<B_ * Q_, 256, 0, stream>>>(out_probs, out_masks, target_masks,
                                             target_labels, tsum, out);
}

// Round 2
// 38.561 us; speedup vs baseline: 2.6897x; 2.6897x over previous
//
#include <hip/hip_runtime.h>
#include <hip/hip_bf16.h>
#include <math.h>

// Problem constants: B=4, Q=100, T=20, H=W=128 (HW=16384), C=80
#define B_ 4
#define Q_ 100
#define T_ 20
#define C_ 80
#define HW_ 16384

#define S_ 8                 // segments over HW
#define QT_ 2                // queries per block
#define PAIRS_ (B_ * Q_ / QT_)   // 200
#define SEG4_ (HW_ / S_ / 4)     // 512 float4 per segment
#define TW_ 5                // t's per wave (4 waves * 5 = T)
#define WREC_ 82             // floats per (pair,seg) record: 2 q * (20 L + 20 I + 1 osum)

__device__ __forceinline__ float wave_reduce_sum(float v) {
    v += __shfl_down(v, 32);
    v += __shfl_down(v, 16);
    v += __shfl_down(v, 8);
    v += __shfl_down(v, 4);
    v += __shfl_down(v, 2);
    v += __shfl_down(v, 1);
    return v;
}

// Kernel 1: per-(b,t) sum of target masks -> tsum[b*T+t]
__global__ __launch_bounds__(256) void tgt_sum_kernel(const float* __restrict__ tgt,
                                                      float* __restrict__ tsum) {
    const int bt = blockIdx.x;
    const float4* p = (const float4*)(tgt + (size_t)bt * HW_);
    float s = 0.f;
    for (int i = threadIdx.x; i < HW_ / 4; i += blockDim.x) {
        float4 v = p[i];
        s += (v.x + v.y) + (v.z + v.w);
    }
    s = wave_reduce_sum(s);
    __shared__ float red[4];
    const int lane = threadIdx.x & 63;
    const int wave = threadIdx.x >> 6;
    if (lane == 0) red[wave] = s;
    __syncthreads();
    if (threadIdx.x == 0) tsum[bt] = red[0] + red[1] + red[2] + red[3];
}

// Kernel 2: partial sums per (pair of queries, segment).
// Each block: 256 threads = 4 waves; wave w handles t in [5w, 5w+5) for both queries.
__global__ __launch_bounds__(256) void partial_kernel(const float* __restrict__ outm,
                                                      const float* __restrict__ tgtm,
                                                      float* __restrict__ ws) {
    const int seg  = blockIdx.x % S_;
    const int pair = blockIdx.x / S_;
    const int b     = pair / (Q_ / QT_);
    const int qbase = (pair % (Q_ / QT_)) * QT_;

    const int lane = threadIdx.x & 63;
    const int wave = threadIdx.x >> 6;
    const int t0   = wave * TW_;

    const float4* o0 = (const float4*)(outm + ((size_t)b * Q_ + qbase) * HW_) + seg * SEG4_;
    const float4* o1 = o0 + (HW_ / 4);   // qbase+1 is contiguous
    const float4* g  = (const float4*)(tgtm + (size_t)b * T_ * HW_) + seg * SEG4_;

    float accL0[TW_], accI0[TW_], accL1[TW_], accI1[TW_];
#pragma unroll
    for (int j = 0; j < TW_; ++j) { accL0[j] = 0.f; accI0[j] = 0.f; accL1[j] = 0.f; accI1[j] = 0.f; }
    float osum0 = 0.f, osum1 = 0.f;

    for (int i = lane; i < SEG4_; i += 64) {
        const float4 a0 = o0[i];
        const float4 a1 = o1[i];
        osum0 += (a0.x + a0.y) + (a0.z + a0.w);
        osum1 += (a1.x + a1.y) + (a1.z + a1.w);
#pragma unroll
        for (int j = 0; j < TW_; ++j) {
            const float4 gv = g[(size_t)(t0 + j) * (HW_ / 4) + i];
            accL0[j] += (fabsf(a0.x - gv.x) + fabsf(a0.y - gv.y)) +
                        (fabsf(a0.z - gv.z) + fabsf(a0.w - gv.w));
            accL1[j] += (fabsf(a1.x - gv.x) + fabsf(a1.y - gv.y)) +
                        (fabsf(a1.z - gv.z) + fabsf(a1.w - gv.w));
            accI0[j] = fmaf(a0.x, gv.x, accI0[j]);
            accI0[j] = fmaf(a0.y, gv.y, accI0[j]);
            accI0[j] = fmaf(a0.z, gv.z, accI0[j]);
            accI0[j] = fmaf(a0.w, gv.w, accI0[j]);
            accI1[j] = fmaf(a1.x, gv.x, accI1[j]);
            accI1[j] = fmaf(a1.y, gv.y, accI1[j]);
            accI1[j] = fmaf(a1.z, gv.z, accI1[j]);
            accI1[j] = fmaf(a1.w, gv.w, accI1[j]);
        }
    }

    // Per-wave reductions; lane 0 writes partial record.
    float* wp = ws + (size_t)(pair * S_ + seg) * WREC_;
#pragma unroll
    for (int j = 0; j < TW_; ++j) {
        float v;
        v = wave_reduce_sum(accL0[j]); if (lane == 0) wp[t0 + j] = v;
        v = wave_reduce_sum(accI0[j]); if (lane == 0) wp[20 + t0 + j] = v;
        v = wave_reduce_sum(accL1[j]); if (lane == 0) wp[41 + t0 + j] = v;
        v = wave_reduce_sum(accI1[j]); if (lane == 0) wp[61 + t0 + j] = v;
    }
    const float v0 = wave_reduce_sum(osum0);
    const float v1 = wave_reduce_sum(osum1);
    if (wave == 0 && lane == 0) { wp[40] = v0; wp[81] = v1; }
}

// Kernel 3: reduce segments + epilogue (softmax class cost + dice).
__global__ __launch_bounds__(64) void finalize_kernel(const float* __restrict__ probs,
                                                      const int*   __restrict__ labels,
                                                      const float* __restrict__ tsum,
                                                      const float* __restrict__ ws,
                                                      float* __restrict__ out) {
    const int bq = blockIdx.x;
    const int b = bq / Q_;
    const int q = bq % Q_;
    const int pair = b * (Q_ / QT_) + (q >> 1);
    const int qi = q & 1;

    __shared__ float s_logit[C_];
    for (int c = threadIdx.x; c < C_; c += 64)
        s_logit[c] = probs[(size_t)bq * C_ + c];
    __syncthreads();

    const int t = threadIdx.x;
    if (t < T_) {
        float L = 0.f, I = 0.f, os = 0.f;
#pragma unroll
        for (int s = 0; s < S_; ++s) {
            const float* wp = ws + (size_t)(pair * S_ + s) * WREC_ + qi * 41;
            L += wp[t];
            I += wp[20 + t];
            os += wp[40];
        }
        float m = -INFINITY;
#pragma unroll
        for (int c = 0; c < C_; ++c) m = fmaxf(m, s_logit[c]);
        float sum = 0.f;
#pragma unroll
        for (int c = 0; c < C_; ++c) sum += __expf(s_logit[c] - m);
        const int lab = labels[b * T_ + t];
        const float p = __expf(s_logit[lab] - m) / sum;

        const float denom = os + tsum[b * T_ + t];
        const float dice = 1.f - (2.f * I + 1.f) / (denom + 1.f);

        out[(size_t)bq * T_ + t] = L - p + dice;
    }
}

extern "C" void kernel_launch(void* const* d_in, const int* in_sizes, int n_in,
                              void* d_out, int out_size, void* d_ws, size_t ws_size,
                              hipStream_t stream) {
    const float* out_probs     = (const float*)d_in[0]; // [B,Q,C]
    const float* out_masks     = (const float*)d_in[1]; // [B,Q,H,W]
    const float* target_masks  = (const float*)d_in[2]; // [B,T,H,W]
    const int*   target_labels = (const int*)d_in[3];   // [B,T]
    float* out = (float*)d_out;                         // [B,Q,T]

    float* tsum     = (float*)d_ws;                     // B*T floats
    float* partials = tsum + B_ * T_;                   // PAIRS_*S_*WREC_ floats (~525 KB)

    tgt_sum_kernel<<<B_ * T_, 256, 0, stream>>>(target_masks, tsum);
    partial_kernel<<<PAIRS_ * S_, 256, 0, stream>>>(out_masks, target_masks, partials);
    finalize_kernel<<<B_ * Q_, 64, 0, stream>>>(out_probs, target_labels, tsum, partials, out);
}